// Round 20
// baseline (63.086 us; speedup 1.0000x reference)
//
#include <hip/hip_runtime.h>
#include <hip/hip_bf16.h>
#include <math.h>

#define NB   64
#define NA   8732
#define NCLS 81
#define NTOT (NB * NA)    // 558848
#define NTILE (NTOT / 16) // 34928 16-anchor tiles, exact
#define NBIN  2048        // linear CE bins, width 1/64 over [0,32)
#define CSCALE 64.0f
#define NSLICE 16         // replication of histogram flush targets
#define K1BLK  1536       // exactly 6 blocks/CU resident; 5.68 tiles/wave
#define SUMBLK 256        // SUM grid

// ---- workspace layout (bytes); [OFF_HISTA, OFF_SCAL+64) is memset to 0 ----
#define OFF_KEYS   0
#define OFF_HISTA  (NTOT * 4)                        // u32[NSLICE][NBIN] = 128 KB
#define OFF_SCAL   (OFF_HISTA + NSLICE * NBIN * 4)   // 64 B
#define OFF_PBNP   (OFF_SCAL + 64)                   // u32[K1BLK]
#define OFF_PBPC   (OFF_PBNP + K1BLK * 4)            // f32[K1BLK]
#define OFF_PBNEG  (OFF_PBPC + K1BLK * 4)            // f32[SUMBLK]
#define OFF_PBLOC  (OFF_PBNEG + SUMBLK * 4)          // f32[SUMBLK]
#define OFF_PBBIN  (OFF_PBLOC + SUMBLK * 4)          // f32[SUMBLK]
#define ZERO_BYTES (NSLICE * NBIN * 4 + 64)
// scal: 0 num_pos(u32), 2 pos_conf(f32), 4 k(u32), 5 bstar(u32; NBIN=none),
//       6 r(u32), 7 h_bin(u32)

// DPP neighbor add (VALU). 0xB1 = quad_perm xor1; 0x4E = quad_perm xor2.
#define DPPF(v, ctrl) \
  __int_as_float(__builtin_amdgcn_update_dpp(0, __float_as_int(v), ctrl, 0xF, 0xF, true))

// 4-byte-aligned float4: gfx9+ global_load_dwordx4 only needs dword alignment.
typedef float f4 __attribute__((ext_vector_type(4)));
typedef f4 __attribute__((aligned(4))) f4u;

// ---------------- Kernel 1: register-direct CE, quad-per-anchor, 3-deep pipeline -----
// Quad (4 lanes) owns one anchor. Lane l loads 5 x dwordx4 at a*324 + 16l + 64j;
// quad holds elements 0..79 in registers; l==0 adds elem 80. Pick via static
// compare/selects (rule #20), e+pick quad-reduced by 2 DPP ops. LDS: only the
// 2048-bin histogram. NO device-scope fences (R9/R15/R18: per-block
// __threadfence ~= per-block L2 writeback; kernel boundary is the cheap release).
__global__ __launch_bounds__(256, 6) void mbl_k1(
    const float* __restrict__ pred_conf, const int* __restrict__ gt_label,
    float* __restrict__ keys, unsigned* __restrict__ hista,
    unsigned* __restrict__ pb_np, float* __restrict__ pb_pc) {
  __shared__ unsigned lhist[NBIN];    // 8192 B
  __shared__ float s_pc[4];
  __shared__ unsigned s_np[4];
  for (int i = threadIdx.x; i < NBIN; i += 256) lhist[i] = 0u;
  __syncthreads();

  const int lane = threadIdx.x & 63;
  const int wid  = threadIdx.x >> 6;
  const int gw   = (blockIdx.x << 2) + wid;   // global wave id, 6144 total
  const int l    = lane & 3;                  // lane within quad
  const int q    = lane >> 2;                 // quad = anchor within tile
  const char* cbase = (const char*)pred_conf;

  float posconf = 0.f;
  unsigned npos = 0u;

  f4 A0, A1, A2, A3, A4; float Ax; int Alab;
  f4 B0, B1, B2, B3, B4; float Bx; int Blab;
  f4 C0, C1, C2, C3, C4; float Cx; int Clab;

#define LOADS(r0, r1, r2, r3, r4, rx, rlab, tt) do {                           \
    const int _a = ((tt) << 4) + q;                                            \
    const char* _p = cbase + (unsigned)_a * 324u + (l << 4);                   \
    r0 = *(const f4u*)(_p);                                                    \
    r1 = *(const f4u*)(_p + 64);                                               \
    r2 = *(const f4u*)(_p + 128);                                              \
    r3 = *(const f4u*)(_p + 192);                                              \
    r4 = *(const f4u*)(_p + 256);                                              \
    rx = (l == 0) ? *(const float*)(cbase + (unsigned)_a * 324u + 320u) : 0.f; \
    rlab = gt_label[_a];                                                       \
  } while (0)

#define COMPUTE(r0, r1, r2, r3, r4, rx, rlab, tt) do {                         \
    float e = 0.f, pk = 0.f;                                                   \
    const int _b = (l << 2);                                                   \
    _Pragma("unroll")                                                          \
    for (int _m = 0; _m < 4; ++_m) {                                           \
      e += __expf(r0[_m]) + __expf(r1[_m]) + __expf(r2[_m])                    \
         + __expf(r3[_m]) + __expf(r4[_m]);                                    \
      if (rlab == _b + _m)      pk = r0[_m];                                   \
      if (rlab == _b + 16 + _m) pk = r1[_m];                                   \
      if (rlab == _b + 32 + _m) pk = r2[_m];                                   \
      if (rlab == _b + 48 + _m) pk = r3[_m];                                   \
      if (rlab == _b + 64 + _m) pk = r4[_m];                                   \
    }                                                                          \
    if (l == 0) {                                                              \
      e += __expf(rx);                                                         \
      if (rlab == 80) pk = rx;                                                 \
    }                                                                          \
    e += DPPF(e, 0xB1);  pk += DPPF(pk, 0xB1);                                 \
    e += DPPF(e, 0x4E);  pk += DPPF(pk, 0x4E);                                 \
    if (l == 0) {                                                              \
      const float ce = __logf(e) - pk;   /* >= 0 */                            \
      const int _a = ((tt) << 4) + q;                                          \
      if (rlab > 0) {                                                          \
        npos += 1u; posconf += ce; keys[_a] = -1.f;                            \
      } else {                                                                 \
        keys[_a] = ce;                                                         \
        int _bin = (int)(ce * CSCALE);                                         \
        _bin = min(_bin, NBIN - 1);                                            \
        atomicAdd(&lhist[_bin], 1u);                                           \
      }                                                                        \
    }                                                                          \
  } while (0)

  // 3-deep rotating pipeline with static register sets (rule #20)
  const int G = K1BLK * 4;
  int i0 = gw;
  bool v0 = i0 < NTILE;
  if (v0) {
    LOADS(A0, A1, A2, A3, A4, Ax, Alab, i0);
    int i1 = i0 + G;
    if (i1 < NTILE) LOADS(B0, B1, B2, B3, B4, Bx, Blab, i1);
    int ic = i1 + G;
    for (;;) {
      if (ic < NTILE) LOADS(C0, C1, C2, C3, C4, Cx, Clab, ic);
      COMPUTE(A0, A1, A2, A3, A4, Ax, Alab, i0);
      if (!(i1 < NTILE)) break;
      const int in = ic + G;
      if (in < NTILE) LOADS(A0, A1, A2, A3, A4, Ax, Alab, in);
      COMPUTE(B0, B1, B2, B3, B4, Bx, Blab, i1);
      if (!(ic < NTILE)) break;
      const int in2 = in + G;
      if (in2 < NTILE) LOADS(B0, B1, B2, B3, B4, Bx, Blab, in2);
      COMPUTE(C0, C1, C2, C3, C4, Cx, Clab, ic);
      if (!(in < NTILE)) break;
      i0 = in; i1 = in2; ic = in2 + G;
    }
  }
#undef LOADS
#undef COMPUTE

#pragma unroll
  for (int s = 1; s < 64; s <<= 1) {
    posconf += __shfl_xor(posconf, s);
    npos    += (unsigned)__shfl_xor((int)npos, s);
  }
  if ((threadIdx.x & 63) == 0) { s_pc[wid] = posconf; s_np[wid] = npos; }
  __syncthreads();   // orders lhist atomics before flush
  if (threadIdx.x == 0) {
    pb_pc[blockIdx.x] = s_pc[0] + s_pc[1] + s_pc[2] + s_pc[3];
    pb_np[blockIdx.x] = s_np[0] + s_np[1] + s_np[2] + s_np[3];
  }
  const unsigned slice_off = (blockIdx.x & (NSLICE - 1)) * NBIN;
  for (int i = threadIdx.x; i < NBIN; i += 256) {
    const unsigned v = lhist[i];
    if (v) atomicAdd(&hista[slice_off + i], v);
  }
}

// ---------------- SEL: reduce partials + single-level bin select (1 block) ----------
__global__ __launch_bounds__(256) void mbl_sel(const unsigned* __restrict__ hista,
                                               const unsigned* __restrict__ pb_np,
                                               const float* __restrict__ pb_pc,
                                               unsigned* __restrict__ scal_u,
                                               float* __restrict__ scal_f) {
  __shared__ unsigned hbin[NBIN];
  __shared__ unsigned partial[256];
  __shared__ float q_pc[4];
  __shared__ unsigned q_np[4];
  __shared__ unsigned s_k;
  const int t = threadIdx.x;

  unsigned np = 0u; float pc = 0.f;
  for (int i = t; i < K1BLK; i += 256) { np += pb_np[i]; pc += pb_pc[i]; }
#pragma unroll
  for (int s = 1; s < 64; s <<= 1) {
    np += (unsigned)__shfl_xor((int)np, s);
    pc += __shfl_xor(pc, s);
  }
  if ((t & 63) == 0) { q_np[t >> 6] = np; q_pc[t >> 6] = pc; }
  __syncthreads();
  if (t == 0) {
    const unsigned tot = q_np[0] + q_np[1] + q_np[2] + q_np[3];
    scal_u[0] = tot;
    scal_f[2] = q_pc[0] + q_pc[1] + q_pc[2] + q_pc[3];
    const unsigned k = min(3u * tot, (unsigned)NTOT - tot);
    s_k = k; scal_u[4] = k;
    if (k == 0u) { scal_u[5] = NBIN; scal_u[6] = 0u; scal_u[7] = 1u; }
  }
  __syncthreads();
  const unsigned k = s_k;
  if (k == 0u) return;

  unsigned s = 0u;
#pragma unroll
  for (int j = 0; j < 8; ++j) {
    unsigned v = 0u;
#pragma unroll
    for (int sl = 0; sl < NSLICE; ++sl) v += hista[sl * NBIN + t * 8 + j];
    hbin[t * 8 + j] = v;
    s += v;
  }
  unsigned val = s;
  partial[t] = val;
  __syncthreads();
  for (int off = 1; off < 256; off <<= 1) {
    const unsigned add = (t + off < 256) ? partial[t + off] : 0u;
    __syncthreads();
    val += add;
    partial[t] = val;
    __syncthreads();
  }
  const unsigned suf = val - s;
  if (suf < k && k <= suf + s) {
    unsigned c = suf;
    for (int b = 7; b >= 0; --b) {
      const unsigned hb = hbin[t * 8 + b];
      if (c + hb >= k) {
        scal_u[5] = (unsigned)(t * 8 + b);
        scal_u[6] = k - c;
        scal_u[7] = hb;
        break;
      }
      c += hb;
    }
  }
}

// ---------------- SUM: neg-CE above bstar + bstar-bin sum + pos smooth-L1 ----------
__global__ __launch_bounds__(256) void mbl_sum(
    const float* __restrict__ keys, const int* __restrict__ gt_label,
    const float* __restrict__ pred_loc, const float* __restrict__ gt_loc,
    const unsigned* __restrict__ scal_u,
    float* __restrict__ pb_neg, float* __restrict__ pb_loc,
    float* __restrict__ pb_bin) {
  __shared__ float q_n[4], q_l[4], q_b[4];
  const int bstar = (int)scal_u[5];
  float acc = 0.f, lacc = 0.f, bacc = 0.f;
  const int stride = gridDim.x * 256;
  for (int i = blockIdx.x * 256 + threadIdx.x; i < NTOT; i += stride) {
    const float kf = keys[i];
    if (kf >= 0.f) {
      int b = (int)(kf * CSCALE);          // bit-identical to K1's binning
      b = min(b, NBIN - 1);
      if (b > bstar) acc += kf;
      else if (b == bstar) bacc += kf;
    }
    const int lb = gt_label[i];
    if (lb > 0) {
      const float4 pl = ((const float4*)pred_loc)[i];
      const float4 gl = ((const float4*)gt_loc)[i];
      float d;
      d = fabsf(pl.x - gl.x); lacc += (d < 1.f) ? 0.5f * d * d : d - 0.5f;
      d = fabsf(pl.y - gl.y); lacc += (d < 1.f) ? 0.5f * d * d : d - 0.5f;
      d = fabsf(pl.z - gl.z); lacc += (d < 1.f) ? 0.5f * d * d : d - 0.5f;
      d = fabsf(pl.w - gl.w); lacc += (d < 1.f) ? 0.5f * d * d : d - 0.5f;
    }
  }
#pragma unroll
  for (int s = 1; s < 64; s <<= 1) {
    acc  += __shfl_xor(acc, s);
    lacc += __shfl_xor(lacc, s);
    bacc += __shfl_xor(bacc, s);
  }
  const int wv = threadIdx.x >> 6;
  if ((threadIdx.x & 63) == 0) { q_n[wv] = acc; q_l[wv] = lacc; q_b[wv] = bacc; }
  __syncthreads();
  if (threadIdx.x == 0) {
    pb_neg[blockIdx.x] = q_n[0] + q_n[1] + q_n[2] + q_n[3];
    pb_loc[blockIdx.x] = q_l[0] + q_l[1] + q_l[2] + q_l[3];
    pb_bin[blockIdx.x] = q_b[0] + q_b[1] + q_b[2] + q_b[3];
  }
}

// ---------------- Finalize ----------------
__global__ __launch_bounds__(256) void mbl_fin(const unsigned* __restrict__ scal_u,
                                               const float* __restrict__ scal_f,
                                               const float* __restrict__ pb_neg,
                                               const float* __restrict__ pb_loc,
                                               const float* __restrict__ pb_bin,
                                               float* __restrict__ out) {
  __shared__ float q_n[4], q_l[4], q_b[4];
  const int t = threadIdx.x;
  float n = pb_neg[t], l = pb_loc[t], b = pb_bin[t];
#pragma unroll
  for (int s = 1; s < 64; s <<= 1) {
    n += __shfl_xor(n, s);
    l += __shfl_xor(l, s);
    b += __shfl_xor(b, s);
  }
  const int wv = t >> 6;
  if ((t & 63) == 0) { q_n[wv] = n; q_l[wv] = l; q_b[wv] = b; }
  __syncthreads();
  if (t == 0) {
    float negsum = q_n[0] + q_n[1] + q_n[2] + q_n[3];
    const float locsum = q_l[0] + q_l[1] + q_l[2] + q_l[3];
    const float binsum = q_b[0] + q_b[1] + q_b[2] + q_b[3];
    const unsigned r = scal_u[6];
    if (r > 0u) negsum += (float)r * (binsum / (float)scal_u[7]);
    out[0] = (locsum + scal_f[2] + negsum) / (float)scal_u[0];
  }
}

extern "C" void kernel_launch(void* const* d_in, const int* in_sizes, int n_in,
                              void* d_out, int out_size, void* d_ws, size_t ws_size,
                              hipStream_t stream) {
  const float* pred_loc  = (const float*)d_in[0];
  const float* pred_conf = (const float*)d_in[1];
  const float* gt_loc    = (const float*)d_in[2];
  const int*   gt_label  = (const int*)d_in[3];
  float* out = (float*)d_out;

  char* ws = (char*)d_ws;
  float*    keys   = (float*)(ws + OFF_KEYS);
  unsigned* hista  = (unsigned*)(ws + OFF_HISTA);
  unsigned* scal_u = (unsigned*)(ws + OFF_SCAL);
  float*    scal_f = (float*)(ws + OFF_SCAL);
  unsigned* pb_np  = (unsigned*)(ws + OFF_PBNP);
  float*    pb_pc  = (float*)(ws + OFF_PBPC);
  float*    pb_neg = (float*)(ws + OFF_PBNEG);
  float*    pb_loc = (float*)(ws + OFF_PBLOC);
  float*    pb_bin = (float*)(ws + OFF_PBBIN);

  // zero hista + scalars (keys/partials fully overwritten every call).
  hipMemsetAsync(ws + OFF_HISTA, 0, ZERO_BYTES, stream);

  mbl_k1<<<K1BLK, 256, 0, stream>>>(pred_conf, gt_label, keys, hista, pb_np, pb_pc);
  mbl_sel<<<1, 256, 0, stream>>>(hista, pb_np, pb_pc, scal_u, scal_f);
  mbl_sum<<<SUMBLK, 256, 0, stream>>>(keys, gt_label, pred_loc, gt_loc, scal_u,
                                      pb_neg, pb_loc, pb_bin);
  mbl_fin<<<1, 256, 0, stream>>>(scal_u, scal_f, pb_neg, pb_loc, pb_bin, out);
}

// Round 21
// 60.571 us; speedup vs baseline: 1.0415x; 1.0415x over previous
//
#include <hip/hip_runtime.h>
#include <hip/hip_bf16.h>
#include <math.h>

#define NB   64
#define NA   8732
#define NCLS 81
#define NTOT (NB * NA)    // 558848
#define NTILE (NTOT / 16) // 34928 16-anchor tiles, exact
#define NBIN  2048        // linear CE bins, width 1/64 over [0,32)
#define CSCALE 64.0f
#define NSLICE 16         // replication of histogram flush targets
#define K1BLK  2048       // best-measured grid (R19: 61.2 us); ~4.26 tiles/wave
#define SUMBLK 256        // SUM grid

// ---- workspace layout (bytes); [OFF_HISTA, OFF_SCAL+64) is memset to 0 ----
#define OFF_KEYS   0
#define OFF_HISTA  (NTOT * 4)                        // u32[NSLICE][NBIN] = 128 KB
#define OFF_SCAL   (OFF_HISTA + NSLICE * NBIN * 4)   // 64 B
#define OFF_PBNP   (OFF_SCAL + 64)                   // u32[K1BLK]
#define OFF_PBPC   (OFF_PBNP + K1BLK * 4)            // f32[K1BLK]
#define OFF_PBNEG  (OFF_PBPC + K1BLK * 4)            // f32[SUMBLK]
#define OFF_PBLOC  (OFF_PBNEG + SUMBLK * 4)          // f32[SUMBLK]
#define OFF_PBBIN  (OFF_PBLOC + SUMBLK * 4)          // f32[SUMBLK]
#define ZERO_BYTES (NSLICE * NBIN * 4 + 64)
// scal: 0 num_pos(u32), 2 pos_conf(f32), 4 k(u32), 5 bstar(u32; NBIN=none),
//       6 r(u32), 7 h_bin(u32)

// DPP neighbor add (VALU). 0xB1 = quad_perm xor1; 0x4E = quad_perm xor2.
#define DPPF(v, ctrl) \
  __int_as_float(__builtin_amdgcn_update_dpp(0, __float_as_int(v), ctrl, 0xF, 0xF, true))

// 4-byte-aligned float4: gfx9+ global_load_dwordx4 only needs dword alignment.
typedef float f4 __attribute__((ext_vector_type(4)));
typedef f4 __attribute__((aligned(4))) f4u;

// ---------------- Kernel 1: register-direct CE, quad-per-anchor (R17/R19 core) -------
// Quad (4 lanes) owns one anchor. Lane l loads 5 x dwordx4 at a*324 + 16l + 64j;
// the quad holds elements 0..79 in registers; l==0 adds elem 80. Pick via 20
// compare/selects (static indexing, rule #20), e+pick quad-reduced by 2 DPP ops.
// LDS: only the 2048-bin histogram. 2-deep prefetch. NO device-scope fences
// (R9/R15/R18 lesson: per-block __threadfence ~= L2 writeback per block;
// kernel boundary is the cheap device-wide release).
__global__ __launch_bounds__(256, 6) void mbl_k1(
    const float* __restrict__ pred_conf, const int* __restrict__ gt_label,
    float* __restrict__ keys, unsigned* __restrict__ hista,
    unsigned* __restrict__ pb_np, float* __restrict__ pb_pc) {
  __shared__ unsigned lhist[NBIN];    // 8192 B
  __shared__ float s_pc[4];
  __shared__ unsigned s_np[4];
  for (int i = threadIdx.x; i < NBIN; i += 256) lhist[i] = 0u;
  __syncthreads();

  const int lane = threadIdx.x & 63;
  const int wid  = threadIdx.x >> 6;
  const int gw   = (blockIdx.x << 2) + wid;   // global wave id, 8192 total
  const int l    = lane & 3;                  // lane within quad
  const int q    = lane >> 2;                 // quad = anchor within tile
  const char* cbase = (const char*)pred_conf;

  float posconf = 0.f;
  unsigned npos = 0u;

  f4 A0, A1, A2, A3, A4; float Ax; int Alab;
  f4 B0, B1, B2, B3, B4; float Bx; int Blab;

#define LOADS(r0, r1, r2, r3, r4, rx, rlab, tt) do {                           \
    const int _a = ((tt) << 4) + q;                                            \
    const char* _p = cbase + (unsigned)_a * 324u + (l << 4);                   \
    r0 = *(const f4u*)(_p);                                                    \
    r1 = *(const f4u*)(_p + 64);                                               \
    r2 = *(const f4u*)(_p + 128);                                              \
    r3 = *(const f4u*)(_p + 192);                                              \
    r4 = *(const f4u*)(_p + 256);                                              \
    rx = (l == 0) ? *(const float*)(cbase + (unsigned)_a * 324u + 320u) : 0.f; \
    rlab = gt_label[_a];                                                       \
  } while (0)

#define COMPUTE(r0, r1, r2, r3, r4, rx, rlab, tt) do {                         \
    float e = 0.f, pk = 0.f;                                                   \
    const int _b = (l << 2);                                                   \
    _Pragma("unroll")                                                          \
    for (int _m = 0; _m < 4; ++_m) {                                           \
      e += __expf(r0[_m]) + __expf(r1[_m]) + __expf(r2[_m])                    \
         + __expf(r3[_m]) + __expf(r4[_m]);                                    \
      if (rlab == _b + _m)      pk = r0[_m];                                   \
      if (rlab == _b + 16 + _m) pk = r1[_m];                                   \
      if (rlab == _b + 32 + _m) pk = r2[_m];                                   \
      if (rlab == _b + 48 + _m) pk = r3[_m];                                   \
      if (rlab == _b + 64 + _m) pk = r4[_m];                                   \
    }                                                                          \
    if (l == 0) {                                                              \
      e += __expf(rx);                                                         \
      if (rlab == 80) pk = rx;                                                 \
    }                                                                          \
    e += DPPF(e, 0xB1);  pk += DPPF(pk, 0xB1);                                 \
    e += DPPF(e, 0x4E);  pk += DPPF(pk, 0x4E);                                 \
    if (l == 0) {                                                              \
      const float ce = __logf(e) - pk;   /* >= 0 */                            \
      const int _a = ((tt) << 4) + q;                                          \
      if (rlab > 0) {                                                          \
        npos += 1u; posconf += ce; keys[_a] = -1.f;                            \
      } else {                                                                 \
        keys[_a] = ce;                                                         \
        int _bin = (int)(ce * CSCALE);                                         \
        _bin = min(_bin, NBIN - 1);                                            \
        atomicAdd(&lhist[_bin], 1u);                                           \
      }                                                                        \
    }                                                                          \
  } while (0)

  // 2-deep rotating pipeline (static register sets, rule #20)
  int i0 = gw;
  const int G = K1BLK * 4;
  bool v0 = i0 < NTILE;
  if (v0) LOADS(A0, A1, A2, A3, A4, Ax, Alab, i0);
  while (v0) {
    const int i1 = i0 + G; const bool v1 = i1 < NTILE;
    if (v1) LOADS(B0, B1, B2, B3, B4, Bx, Blab, i1);
    COMPUTE(A0, A1, A2, A3, A4, Ax, Alab, i0);
    if (!v1) break;
    const int i2 = i1 + G; const bool v2 = i2 < NTILE;
    if (v2) LOADS(A0, A1, A2, A3, A4, Ax, Alab, i2);
    COMPUTE(B0, B1, B2, B3, B4, Bx, Blab, i1);
    i0 = i2; v0 = v2;
  }
#undef LOADS
#undef COMPUTE

#pragma unroll
  for (int s = 1; s < 64; s <<= 1) {
    posconf += __shfl_xor(posconf, s);
    npos    += (unsigned)__shfl_xor((int)npos, s);
  }
  if ((threadIdx.x & 63) == 0) { s_pc[wid] = posconf; s_np[wid] = npos; }
  __syncthreads();   // orders lhist atomics before flush
  if (threadIdx.x == 0) {
    pb_pc[blockIdx.x] = s_pc[0] + s_pc[1] + s_pc[2] + s_pc[3];
    pb_np[blockIdx.x] = s_np[0] + s_np[1] + s_np[2] + s_np[3];
  }
  const unsigned slice_off = (blockIdx.x & (NSLICE - 1)) * NBIN;
  for (int i = threadIdx.x; i < NBIN; i += 256) {
    const unsigned v = lhist[i];
    if (v) atomicAdd(&hista[slice_off + i], v);
  }
}

// ---------------- SEL: reduce partials + single-level bin select (1 block) ----------
__global__ __launch_bounds__(256) void mbl_sel(const unsigned* __restrict__ hista,
                                               const unsigned* __restrict__ pb_np,
                                               const float* __restrict__ pb_pc,
                                               unsigned* __restrict__ scal_u,
                                               float* __restrict__ scal_f) {
  __shared__ unsigned hbin[NBIN];
  __shared__ unsigned partial[256];
  __shared__ float q_pc[4];
  __shared__ unsigned q_np[4];
  __shared__ unsigned s_k;
  const int t = threadIdx.x;

  unsigned np = 0u; float pc = 0.f;
  for (int i = t; i < K1BLK; i += 256) { np += pb_np[i]; pc += pb_pc[i]; }
#pragma unroll
  for (int s = 1; s < 64; s <<= 1) {
    np += (unsigned)__shfl_xor((int)np, s);
    pc += __shfl_xor(pc, s);
  }
  if ((t & 63) == 0) { q_np[t >> 6] = np; q_pc[t >> 6] = pc; }
  __syncthreads();
  if (t == 0) {
    const unsigned tot = q_np[0] + q_np[1] + q_np[2] + q_np[3];
    scal_u[0] = tot;
    scal_f[2] = q_pc[0] + q_pc[1] + q_pc[2] + q_pc[3];
    const unsigned k = min(3u * tot, (unsigned)NTOT - tot);
    s_k = k; scal_u[4] = k;
    if (k == 0u) { scal_u[5] = NBIN; scal_u[6] = 0u; scal_u[7] = 1u; }
  }
  __syncthreads();
  const unsigned k = s_k;
  if (k == 0u) return;

  unsigned s = 0u;
#pragma unroll
  for (int j = 0; j < 8; ++j) {
    unsigned v = 0u;
#pragma unroll
    for (int sl = 0; sl < NSLICE; ++sl) v += hista[sl * NBIN + t * 8 + j];
    hbin[t * 8 + j] = v;
    s += v;
  }
  unsigned val = s;
  partial[t] = val;
  __syncthreads();
  for (int off = 1; off < 256; off <<= 1) {
    const unsigned add = (t + off < 256) ? partial[t + off] : 0u;
    __syncthreads();
    val += add;
    partial[t] = val;
    __syncthreads();
  }
  const unsigned suf = val - s;
  if (suf < k && k <= suf + s) {
    unsigned c = suf;
    for (int b = 7; b >= 0; --b) {
      const unsigned hb = hbin[t * 8 + b];
      if (c + hb >= k) {
        scal_u[5] = (unsigned)(t * 8 + b);
        scal_u[6] = k - c;
        scal_u[7] = hb;
        break;
      }
      c += hb;
    }
  }
}

// ---------------- SUM: neg-CE above bstar + bstar-bin sum + pos smooth-L1 ----------
__global__ __launch_bounds__(256) void mbl_sum(
    const float* __restrict__ keys, const int* __restrict__ gt_label,
    const float* __restrict__ pred_loc, const float* __restrict__ gt_loc,
    const unsigned* __restrict__ scal_u,
    float* __restrict__ pb_neg, float* __restrict__ pb_loc,
    float* __restrict__ pb_bin) {
  __shared__ float q_n[4], q_l[4], q_b[4];
  const int bstar = (int)scal_u[5];
  float acc = 0.f, lacc = 0.f, bacc = 0.f;
  const int stride = gridDim.x * 256;
  for (int i = blockIdx.x * 256 + threadIdx.x; i < NTOT; i += stride) {
    const float kf = keys[i];
    if (kf >= 0.f) {
      int b = (int)(kf * CSCALE);          // bit-identical to K1's binning
      b = min(b, NBIN - 1);
      if (b > bstar) acc += kf;
      else if (b == bstar) bacc += kf;
    }
    const int lb = gt_label[i];
    if (lb > 0) {
      const float4 pl = ((const float4*)pred_loc)[i];
      const float4 gl = ((const float4*)gt_loc)[i];
      float d;
      d = fabsf(pl.x - gl.x); lacc += (d < 1.f) ? 0.5f * d * d : d - 0.5f;
      d = fabsf(pl.y - gl.y); lacc += (d < 1.f) ? 0.5f * d * d : d - 0.5f;
      d = fabsf(pl.z - gl.z); lacc += (d < 1.f) ? 0.5f * d * d : d - 0.5f;
      d = fabsf(pl.w - gl.w); lacc += (d < 1.f) ? 0.5f * d * d : d - 0.5f;
    }
  }
#pragma unroll
  for (int s = 1; s < 64; s <<= 1) {
    acc  += __shfl_xor(acc, s);
    lacc += __shfl_xor(lacc, s);
    bacc += __shfl_xor(bacc, s);
  }
  const int wv = threadIdx.x >> 6;
  if ((threadIdx.x & 63) == 0) { q_n[wv] = acc; q_l[wv] = lacc; q_b[wv] = bacc; }
  __syncthreads();
  if (threadIdx.x == 0) {
    pb_neg[blockIdx.x] = q_n[0] + q_n[1] + q_n[2] + q_n[3];
    pb_loc[blockIdx.x] = q_l[0] + q_l[1] + q_l[2] + q_l[3];
    pb_bin[blockIdx.x] = q_b[0] + q_b[1] + q_b[2] + q_b[3];
  }
}

// ---------------- Finalize ----------------
__global__ __launch_bounds__(256) void mbl_fin(const unsigned* __restrict__ scal_u,
                                               const float* __restrict__ scal_f,
                                               const float* __restrict__ pb_neg,
                                               const float* __restrict__ pb_loc,
                                               const float* __restrict__ pb_bin,
                                               float* __restrict__ out) {
  __shared__ float q_n[4], q_l[4], q_b[4];
  const int t = threadIdx.x;
  float n = pb_neg[t], l = pb_loc[t], b = pb_bin[t];
#pragma unroll
  for (int s = 1; s < 64; s <<= 1) {
    n += __shfl_xor(n, s);
    l += __shfl_xor(l, s);
    b += __shfl_xor(b, s);
  }
  const int wv = t >> 6;
  if ((t & 63) == 0) { q_n[wv] = n; q_l[wv] = l; q_b[wv] = b; }
  __syncthreads();
  if (t == 0) {
    float negsum = q_n[0] + q_n[1] + q_n[2] + q_n[3];
    const float locsum = q_l[0] + q_l[1] + q_l[2] + q_l[3];
    const float binsum = q_b[0] + q_b[1] + q_b[2] + q_b[3];
    const unsigned r = scal_u[6];
    if (r > 0u) negsum += (float)r * (binsum / (float)scal_u[7]);
    out[0] = (locsum + scal_f[2] + negsum) / (float)scal_u[0];
  }
}

extern "C" void kernel_launch(void* const* d_in, const int* in_sizes, int n_in,
                              void* d_out, int out_size, void* d_ws, size_t ws_size,
                              hipStream_t stream) {
  const float* pred_loc  = (const float*)d_in[0];
  const float* pred_conf = (const float*)d_in[1];
  const float* gt_loc    = (const float*)d_in[2];
  const int*   gt_label  = (const int*)d_in[3];
  float* out = (float*)d_out;

  char* ws = (char*)d_ws;
  float*    keys   = (float*)(ws + OFF_KEYS);
  unsigned* hista  = (unsigned*)(ws + OFF_HISTA);
  unsigned* scal_u = (unsigned*)(ws + OFF_SCAL);
  float*    scal_f = (float*)(ws + OFF_SCAL);
  unsigned* pb_np  = (unsigned*)(ws + OFF_PBNP);
  float*    pb_pc  = (float*)(ws + OFF_PBPC);
  float*    pb_neg = (float*)(ws + OFF_PBNEG);
  float*    pb_loc = (float*)(ws + OFF_PBLOC);
  float*    pb_bin = (float*)(ws + OFF_PBBIN);

  // zero hista + scalars (keys/partials fully overwritten every call).
  hipMemsetAsync(ws + OFF_HISTA, 0, ZERO_BYTES, stream);

  mbl_k1<<<K1BLK, 256, 0, stream>>>(pred_conf, gt_label, keys, hista, pb_np, pb_pc);
  mbl_sel<<<1, 256, 0, stream>>>(hista, pb_np, pb_pc, scal_u, scal_f);
  mbl_sum<<<SUMBLK, 256, 0, stream>>>(keys, gt_label, pred_loc, gt_loc, scal_u,
                                      pb_neg, pb_loc, pb_bin);
  mbl_fin<<<1, 256, 0, stream>>>(scal_u, scal_f, pb_neg, pb_loc, pb_bin, out);
}